// Round 6
// baseline (102.499 us; speedup 1.0000x reference)
//
#include <hip/hip_runtime.h>
#include <hip/hip_bf16.h>
#include <math.h>

#define BB 32
#define NP 576
#define WW 32
#define DD 256
// GEMM view: M = 18432, N = 1024, K = 256. 160 M-tiles (5/image, last 64-valid)
// x 8 N-tiles = 1280 blocks.
//
// Intermediate layout (MFMA-ready, verified rounds 4-5):
// per 16-row group g: 8 segs of 512 bf16 (1 KiB), seg s = kb*2 + kk.
// Within a seg, index (q*16+r)*8+j <-> (row g*16+r, k = kb*64+kk*32+q*8+j) —
// exactly the 16x16x32 fragment image for lane l = q*16+r. So a wave reading
// base + lane*16 gets a coalesced 1-KiB transaction in frag order, usable both
// for global_load_lds (A) and direct global->VGPR frag loads (B).

typedef __bf16 bf16x8 __attribute__((ext_vector_type(8)));
typedef float f32x4 __attribute__((ext_vector_type(4)));

__device__ __forceinline__ unsigned short f2bf(float f) {
  unsigned int u = __float_as_uint(f);
  u += 0x7FFFu + ((u >> 16) & 1u);
  return (unsigned short)(u >> 16);
}

__device__ __forceinline__ void gld_lds16(const unsigned short* g, unsigned short* l) {
  __builtin_amdgcn_global_load_lds(
      (const __attribute__((address_space(1))) void*)g,
      (__attribute__((address_space(3))) void*)l, 16, 0, 0);
}

// Order-preserving float<->uint map for atomicMax; 0 is below any encoded real
// (cos-sims are finite, so every encoded value is > 0).
__device__ __forceinline__ unsigned int encf(float f) {
  unsigned int b = __float_as_uint(f);
  return (b & 0x80000000u) ? ~b : (b | 0x80000000u);
}
__device__ __forceinline__ float decf(unsigned int u) {
  unsigned int b = (u & 0x80000000u) ? (u & 0x7FFFFFFFu) : ~u;
  return __uint_as_float(b);
}

// Kernel A: L2-normalize + bf16 cast + tiled-layout shuffle; also zeroes the
// atomicMax targets (blocks 0..127) — kernel-boundary ordering makes the
// zeros visible to the gemm kernel.
__global__ __launch_bounds__(256) void norm_cast_kernel(
    const float* __restrict__ img, const float* __restrict__ con,
    unsigned short* __restrict__ img_t, unsigned short* __restrict__ con_t,
    unsigned int* __restrict__ sraw) {
  int gid = blockIdx.x * 256 + threadIdx.x;
  if (gid < BB * 1024) sraw[gid] = 0u;

  int row = blockIdx.x * 4 + (threadIdx.x >> 6);
  int lane = threadIdx.x & 63;
  const int n_img = BB * NP;  // 18432
  const float* src;
  unsigned short* dstbase;
  int prow;
  if (row < n_img) {
    src = img + (size_t)row * DD;
    dstbase = img_t;
    prow = row;
  } else {
    prow = row - n_img;
    src = con + (size_t)prow * DD;
    dstbase = con_t;
  }
  float4 v = ((const float4*)src)[lane];
  float ss = v.x * v.x + v.y * v.y + v.z * v.z + v.w * v.w;
  #pragma unroll
  for (int off = 1; off < 64; off <<= 1) ss += __shfl_xor(ss, off);
  float inv = 1.0f / fmaxf(sqrtf(ss), 1e-12f);
  ushort4 o;
  o.x = f2bf(v.x * inv);
  o.y = f2bf(v.y * inv);
  o.z = f2bf(v.z * inv);
  o.w = f2bf(v.w * inv);
  size_t di = ((size_t)(prow >> 4) * 8 + (lane >> 3)) * 512 +
              (size_t)((((lane >> 1) & 3) * 16 + (prow & 15)) * 8) + (lane & 1) * 4;
  *(ushort4*)(dstbase + di) = o;
}

// Kernel B: 128x128-tile GEMM (BK=64), A staged via global_load_lds (only
// operand behind the barrier), B loaded per-chunk straight into VGPR frags
// (L2-hot, no barrier dependency -> overlaps across waves). Max epilogue
// feeds atomicMax on encoded floats.
// Frag layouts (verified rounds 1-4): A-frag lane(q,r) = A[row=r][k=q*8+j];
// D: row = q*4+reg, col = r.
__global__ __launch_bounds__(256, 3) void gemm_max_kernel(
    const unsigned short* __restrict__ img_t,  // tiled 18432 x 256
    const unsigned short* __restrict__ con_t,  // tiled 1024 x 256
    unsigned int* __restrict__ sraw) {         // [32][1024] encoded maxes
  int bx = blockIdx.x;
  int bw = bx & 7;    // N-tile 0..7
  int bm = bx >> 3;   // M-tile 0..159
  int m = bm / 5;
  int t = bm - m * 5;
  int p0 = m * NP + t * 128;  // t==4: rows 64..127 invalid
  int w0 = bw * 128;

  __shared__ __align__(16) unsigned short ldsA[8192];  // 16 segs x 512 = 16 KB
  __shared__ float sm[256];

  int tid = threadIdx.x;
  int wid = tid >> 6;
  int lane = tid & 63;
  int wp = wid >> 1;  // row-half
  int wc = wid & 1;   // col-half

  f32x4 acc[4][4];
  #pragma unroll
  for (int i = 0; i < 4; ++i)
    #pragma unroll
    for (int j = 0; j < 4; ++j) acc[i][j] = (f32x4){0.f, 0.f, 0.f, 0.f};

  const unsigned short* gA = img_t + (size_t)(p0 >> 4) * 4096 + lane * 8;
  // B base for this wave's col-half: 16-col groups wc*4 + wj.
  const unsigned short* gB = con_t + ((size_t)(w0 >> 4) + wc * 4) * 4096 + lane * 8;

  for (int kb = 0; kb < 4; ++kb) {
    __syncthreads();  // previous chunk's ldsA fully consumed
    #pragma unroll
    for (int u = 0; u < 4; ++u) {
      int s = wid * 4 + u;  // A seg 0..15 (wave-uniform)
      int gi = s >> 1;
      int kk2 = s & 1;
      gld_lds16(gA + ((size_t)gi * 8 + kb * 2 + kk2) * 512, &ldsA[s * 512]);
    }
    // B frags for this chunk: 4 col-groups x 2 K-halves, direct to VGPRs.
    bf16x8 bfr[4][2];
    #pragma unroll
    for (int wj = 0; wj < 4; ++wj)
      #pragma unroll
      for (int kk = 0; kk < 2; ++kk)
        bfr[wj][kk] =
            *(const bf16x8*)(gB + ((size_t)wj * 8 + kb * 2 + kk) * 512);
    __syncthreads();  // drains A-DMA (vmcnt) for all waves
    #pragma unroll
    for (int kk = 0; kk < 2; ++kk) {
      bf16x8 af[4];
      #pragma unroll
      for (int pi = 0; pi < 4; ++pi)
        af[pi] = *(const bf16x8*)&ldsA[(((wp * 4 + pi) << 1) | kk) * 512 + lane * 8];
      #pragma unroll
      for (int pi = 0; pi < 4; ++pi)
        #pragma unroll
        for (int wj = 0; wj < 4; ++wj)
          acc[pi][wj] = __builtin_amdgcn_mfma_f32_16x16x32_bf16(
              af[pi], bfr[wj][kk], acc[pi][wj], 0, 0, 0);
    }
  }

  // Epilogue: max over this wave's 64 rows for each of its 64 cols.
  float mxw[4];
  #pragma unroll
  for (int wj = 0; wj < 4; ++wj) {
    float v = -1e30f;
    #pragma unroll
    for (int pi = 0; pi < 4; ++pi)
      v = fmaxf(v, fmaxf(fmaxf(acc[pi][wj][0], acc[pi][wj][1]),
                         fmaxf(acc[pi][wj][2], acc[pi][wj][3])));
    v = fmaxf(v, __shfl_xor(v, 16));
    v = fmaxf(v, __shfl_xor(v, 32));
    mxw[wj] = v;
  }
  __syncthreads();
  if (lane < 16) {
    #pragma unroll
    for (int wj = 0; wj < 4; ++wj)
      sm[wp * 128 + wc * 64 + wj * 16 + lane] = mxw[wj];
  }
  __syncthreads();
  if (tid < 128) {
    float v = sm[tid];                        // rows 0..63 always valid
    if (t != 4) v = fmaxf(v, sm[128 + tid]);  // rows 64..127 only if valid
    atomicMax(&sraw[(size_t)m * 1024 + w0 + tid], encf(v));
  }
}

// Kernel C: masked mean over valid concepts + SigLIP loss. One 1024-thread
// block; thread p handles pair (m = p>>5, c = p&31).
__global__ __launch_bounds__(1024) void loss_kernel(
    const unsigned int* __restrict__ sraw, const int* __restrict__ lens,
    const float* __restrict__ lsc, const float* __restrict__ lbi,
    float* __restrict__ out) {
  int tid = threadIdx.x;
  int m = tid >> 5;
  int c = tid & 31;
  int len = lens[c];
  const unsigned int* base = sraw + (size_t)m * 1024 + c * 32;
  float s = 0.0f;
  for (int w = 0; w < WW; ++w)
    if (w < len) s += decf(base[w]);
  s /= (float)len;
  float tt = expf(fminf(fmaxf(lsc[0], -10.0f), 10.0f));
  float lg = fminf(fmaxf(tt * s + lbi[0], -50.0f), 50.0f);
  float x = (m == c) ? lg : -lg;
  float acc = (x >= 0.0f) ? -log1pf(expf(-x)) : (x - log1pf(expf(x)));
  #pragma unroll
  for (int off = 1; off < 64; off <<= 1) acc += __shfl_xor(acc, off);
  __shared__ float sred[16];
  if ((tid & 63) == 0) sred[tid >> 6] = acc;
  __syncthreads();
  if (tid == 0) {
    float tot = 0.0f;
    #pragma unroll
    for (int i = 0; i < 16; ++i) tot += sred[i];
    out[0] = -tot / (float)(BB * BB);
  }
}

extern "C" void kernel_launch(void* const* d_in, const int* in_sizes, int n_in,
                              void* d_out, int out_size, void* d_ws, size_t ws_size,
                              hipStream_t stream) {
  const float* img = (const float*)d_in[0];  // (32, 576, 256) f32
  const float* con = (const float*)d_in[1];  // (32, 32, 256) f32
  const int* lens = (const int*)d_in[2];     // (32,) i32
  const float* lsc = (const float*)d_in[3];  // (1,)
  const float* lbi = (const float*)d_in[4];  // (1,)

  unsigned short* img_t = (unsigned short*)d_ws;           // 18432*256 bf16, tiled
  unsigned short* con_t = img_t + (size_t)BB * NP * DD;    // 1024*256 bf16, tiled
  unsigned int* sraw = (unsigned int*)(con_t + (size_t)BB * WW * DD);  // 32*1024

  norm_cast_kernel<<<(BB * NP + BB * WW) / 4, 256, 0, stream>>>(img, con, img_t,
                                                                con_t, sraw);
  gemm_max_kernel<<<160 * 8, 256, 0, stream>>>(img_t, con_t, sraw);
  loss_kernel<<<1, 1024, 0, stream>>>(sraw, lens, lsc, lbi, (float*)d_out);
}

// Round 7
// 97.737 us; speedup vs baseline: 1.0487x; 1.0487x over previous
//
#include <hip/hip_runtime.h>
#include <hip/hip_bf16.h>
#include <math.h>

#define BB 32
#define NP 576
#define WW 32
#define DD 256
// GEMM view: M = 18432, N = 1024, K = 256. 160 M-tiles (5/image, last 64-valid)
// x 8 N-tiles = 1280 blocks.
//
// Tiled intermediate layout (MFMA-ready, verified rounds 4-6):
// per 16-row group g: 8 segs of 512 bf16 (1 KiB), seg s = kb*2 + kk.
// Within a seg, index (q*16+r)*8+j <-> (row g*16+r, k = kb*64+kk*32+q*8+j) —
// exactly the 16x16x32 fragment image for lane l = q*16+r, so a wave reading
// base + lane*16 is one coalesced 1-KiB transaction in frag order.

typedef __bf16 bf16x8 __attribute__((ext_vector_type(8)));
typedef float f32x4 __attribute__((ext_vector_type(4)));

__device__ __forceinline__ unsigned short f2bf(float f) {
  unsigned int u = __float_as_uint(f);
  u += 0x7FFFu + ((u >> 16) & 1u);
  return (unsigned short)(u >> 16);
}

__device__ __forceinline__ void gld_lds16(const unsigned short* g, unsigned short* l) {
  __builtin_amdgcn_global_load_lds(
      (const __attribute__((address_space(1))) void*)g,
      (__attribute__((address_space(3))) void*)l, 16, 0, 0);
}

// Order-preserving float<->uint map for atomicMax; 0 is below any encoded real.
__device__ __forceinline__ unsigned int encf(float f) {
  unsigned int b = __float_as_uint(f);
  return (b & 0x80000000u) ? ~b : (b | 0x80000000u);
}
__device__ __forceinline__ float decf(unsigned int u) {
  unsigned int b = (u & 0x80000000u) ? (u & 0x7FFFFFFFu) : ~u;
  return __uint_as_float(b);
}

// Kernel A: L2-normalize + bf16 cast + tiled-layout shuffle, one 1024-thread
// block per 16-row group. Wave w normalizes row w into padded LDS (stride 264
// shorts -> 2-way banks, free); copy-out emits the group's 8-KB tiled image as
// one fully-coalesced store. Tiled short-index i decodes as: s=i>>9, idx8 =
// (i&511)>>3, q=idx8>>4, r=idx8&15, ji=i&7, k=(s>>1)*64+(s&1)*32+q*8+ji, and
// the source element is lds[row r][k] (k == original element index; algebra
// matches the round-4 per-lane store mapping exactly).
__global__ __launch_bounds__(1024) void norm_cast_kernel(
    const float* __restrict__ img, const float* __restrict__ con,
    unsigned short* __restrict__ img_t, unsigned short* __restrict__ con_t,
    unsigned int* __restrict__ sraw) {
  __shared__ __align__(16) unsigned short lds[16 * 264];
  int tid = threadIdx.x;
  int g = blockIdx.x;  // group 0..1215
  if (g < 32) sraw[g * 1024 + tid] = 0u;  // zero atomicMax targets (32*1024)

  int w = tid >> 6;  // row-in-group
  int L = tid & 63;
  const int n_img_g = (BB * NP) >> 4;  // 1152 img groups
  const float* src;
  unsigned short* dstbase;
  int gl;
  if (g < n_img_g) {
    src = img + ((size_t)g * 16 + w) * DD;
    dstbase = img_t;
    gl = g;
  } else {
    gl = g - n_img_g;
    src = con + ((size_t)gl * 16 + w) * DD;
    dstbase = con_t;
  }
  float4 v = ((const float4*)src)[L];
  float ss = v.x * v.x + v.y * v.y + v.z * v.z + v.w * v.w;
  #pragma unroll
  for (int off = 1; off < 64; off <<= 1) ss += __shfl_xor(ss, off);
  float inv = 1.0f / fmaxf(sqrtf(ss), 1e-12f);
  ushort4 o;
  o.x = f2bf(v.x * inv);
  o.y = f2bf(v.y * inv);
  o.z = f2bf(v.z * inv);
  o.w = f2bf(v.w * inv);
  *(ushort4*)&lds[w * 264 + L * 4] = o;
  __syncthreads();
  int i = tid * 4;
  int s = i >> 9;
  int idx8 = (i & 511) >> 3;
  int q = idx8 >> 4;
  int r = idx8 & 15;
  int ji = i & 7;  // 0 or 4
  int k = (s >> 1) * 64 + (s & 1) * 32 + q * 8 + ji;
  ushort4 val = *(const ushort4*)&lds[r * 264 + k];
  *(ushort4*)(dstbase + (size_t)gl * 4096 + i) = val;
}

// Kernel B: 128x128-tile GEMM (BK=64), both operands staged via
// global_load_lds (round-4 verified body), with XCD-aware block swizzle:
// assuming round-robin blockIdx->XCD, XCD x = bx&7 processes all 8 N-tiles of
// each of its M-tiles consecutively -> A M-tile fetched from L3 once, then
// L2-hit; B (512 KB) stays L2-resident per XCD. Max epilogue -> atomicMax.
// Frag layouts (verified rounds 1-6): A-frag lane(q,r) = A[row=r][k=q*8+j];
// D: row = q*4+reg, col = r.
__global__ __launch_bounds__(256, 3) void gemm_max_kernel(
    const unsigned short* __restrict__ img_t,  // tiled 18432 x 256
    const unsigned short* __restrict__ con_t,  // tiled 1024 x 256
    unsigned int* __restrict__ sraw) {         // [32][1024] encoded maxes
  int bx = blockIdx.x;
  int xcd = bx & 7;
  int k2 = bx >> 3;            // 0..159
  int bm = (k2 & ~7) | xcd;    // M-tile 0..159 (each on exactly one XCD)
  int bw = k2 & 7;             // N-tile 0..7
  int m = bm / 5;
  int t = bm - m * 5;
  int p0 = m * NP + t * 128;  // t==4: rows 64..127 invalid
  int w0 = bw * 128;

  __shared__ __align__(16) unsigned short ldsA[8192];  // 16 segs x 512 = 16 KB
  __shared__ __align__(16) unsigned short ldsB[8192];
  __shared__ float sm[256];

  int tid = threadIdx.x;
  int wid = tid >> 6;
  int lane = tid & 63;
  int wp = wid >> 1;  // row-half
  int wc = wid & 1;   // col-half

  f32x4 acc[4][4];
  #pragma unroll
  for (int i = 0; i < 4; ++i)
    #pragma unroll
    for (int j = 0; j < 4; ++j) acc[i][j] = (f32x4){0.f, 0.f, 0.f, 0.f};

  const unsigned short* gA = img_t + (size_t)(p0 >> 4) * 4096 + lane * 8;
  const unsigned short* gB = con_t + (size_t)(w0 >> 4) * 4096 + lane * 8;

  for (int kb = 0; kb < 4; ++kb) {
    __syncthreads();  // previous chunk's LDS fully consumed
    #pragma unroll
    for (int u = 0; u < 4; ++u) {
      int s = wid * 4 + u;  // seg 0..15 (wave-uniform)
      int gi = s >> 1;
      int kk2 = s & 1;
      size_t goff = ((size_t)gi * 8 + kb * 2 + kk2) * 512;
      gld_lds16(gA + goff, &ldsA[s * 512]);
      gld_lds16(gB + goff, &ldsB[s * 512]);
    }
    __syncthreads();  // drains vmcnt (DMA complete) for all waves
    #pragma unroll
    for (int kk = 0; kk < 2; ++kk) {
      bf16x8 af[4], bfr[4];
      #pragma unroll
      for (int pi = 0; pi < 4; ++pi)
        af[pi] = *(const bf16x8*)&ldsA[(((wp * 4 + pi) << 1) | kk) * 512 + lane * 8];
      #pragma unroll
      for (int wj = 0; wj < 4; ++wj)
        bfr[wj] = *(const bf16x8*)&ldsB[(((wc * 4 + wj) << 1) | kk) * 512 + lane * 8];
      #pragma unroll
      for (int pi = 0; pi < 4; ++pi)
        #pragma unroll
        for (int wj = 0; wj < 4; ++wj)
          acc[pi][wj] = __builtin_amdgcn_mfma_f32_16x16x32_bf16(af[pi], bfr[wj],
                                                                acc[pi][wj], 0, 0, 0);
    }
  }

  // Epilogue: max over this wave's 64 rows for each of its 64 cols.
  float mxw[4];
  #pragma unroll
  for (int wj = 0; wj < 4; ++wj) {
    float v = -1e30f;
    #pragma unroll
    for (int pi = 0; pi < 4; ++pi)
      v = fmaxf(v, fmaxf(fmaxf(acc[pi][wj][0], acc[pi][wj][1]),
                         fmaxf(acc[pi][wj][2], acc[pi][wj][3])));
    v = fmaxf(v, __shfl_xor(v, 16));
    v = fmaxf(v, __shfl_xor(v, 32));
    mxw[wj] = v;
  }
  __syncthreads();
  if (lane < 16) {
    #pragma unroll
    for (int wj = 0; wj < 4; ++wj)
      sm[wp * 128 + wc * 64 + wj * 16 + lane] = mxw[wj];
  }
  __syncthreads();
  if (tid < 128) {
    float v = sm[tid];                        // rows 0..63 always valid
    if (t != 4) v = fmaxf(v, sm[128 + tid]);  // rows 64..127 only if valid
    atomicMax(&sraw[(size_t)m * 1024 + w0 + tid], encf(v));
  }
}

// Kernel C: masked mean + SigLIP loss, one 1024-thread block (verified R6).
__global__ __launch_bounds__(1024) void loss_kernel(
    const unsigned int* __restrict__ sraw, const int* __restrict__ lens,
    const float* __restrict__ lsc, const float* __restrict__ lbi,
    float* __restrict__ out) {
  int tid = threadIdx.x;
  int m = tid >> 5;
  int c = tid & 31;
  int len = lens[c];
  const unsigned int* base = sraw + (size_t)m * 1024 + c * 32;
  float s = 0.0f;
  for (int w = 0; w < WW; ++w)
    if (w < len) s += decf(base[w]);
  s /= (float)len;
  float tt = expf(fminf(fmaxf(lsc[0], -10.0f), 10.0f));
  float lg = fminf(fmaxf(tt * s + lbi[0], -50.0f), 50.0f);
  float x = (m == c) ? lg : -lg;
  float acc = (x >= 0.0f) ? -log1pf(expf(-x)) : (x - log1pf(expf(x)));
  #pragma unroll
  for (int off = 1; off < 64; off <<= 1) acc += __shfl_xor(acc, off);
  __shared__ float sred[16];
  if ((tid & 63) == 0) sred[tid >> 6] = acc;
  __syncthreads();
  if (tid == 0) {
    float tot = 0.0f;
    #pragma unroll
    for (int i = 0; i < 16; ++i) tot += sred[i];
    out[0] = -tot / (float)(BB * BB);
  }
}

extern "C" void kernel_launch(void* const* d_in, const int* in_sizes, int n_in,
                              void* d_out, int out_size, void* d_ws, size_t ws_size,
                              hipStream_t stream) {
  const float* img = (const float*)d_in[0];  // (32, 576, 256) f32
  const float* con = (const float*)d_in[1];  // (32, 32, 256) f32
  const int* lens = (const int*)d_in[2];     // (32,) i32
  const float* lsc = (const float*)d_in[3];  // (1,)
  const float* lbi = (const float*)d_in[4];  // (1,)

  unsigned short* img_t = (unsigned short*)d_ws;           // 18432*256 bf16, tiled
  unsigned short* con_t = img_t + (size_t)BB * NP * DD;    // 1024*256 bf16, tiled
  unsigned int* sraw = (unsigned int*)(con_t + (size_t)BB * WW * DD);  // 32*1024

  norm_cast_kernel<<<1152 + 64, 1024, 0, stream>>>(img, con, img_t, con_t, sraw);
  gemm_max_kernel<<<160 * 8, 256, 0, stream>>>(img_t, con_t, sraw);
  loss_kernel<<<1, 1024, 0, stream>>>(sraw, lens, lsc, lbi, (float*)d_out);
}